// Round 12
// baseline (30.806 us; speedup 1.0000x reference)
//
#include <hip/hip_runtime.h>

#define N1 8192
#define N2 8192
#define KNN 32
#define R2_F32 0.009999999776482582f   // f32(0.1*0.1), bit-exact vs np ref (rounds 2..11)

#define GDIM 10
#define NCELLS (GDIM * GDIM * GDIM)
// cell width 7/64 = 0.109375 exactly; INV_W = 64/7. Non-adjacent cells => gap >= 0.1093
// => true d2 >= 0.0119 >> 0.01 + gram-noise(6e-7): grid can never drop a reference hit.
#define INV_W 9.142857142857142f
#define HCAP 128   // per-query hit buffer (E[hits]~34; P(>128) ~ 0)

// ---- ws layout (bytes) ----
// 0      : counts  [1000] i32   (memsetAsync'd to 0 each launch)
// 4096   : off     [1001] i32
// 12288  : cursor  [1000] i32
// 16384  : pts4    [8192] float4 (x,y,z,(float)j), grouped by cell
#define WS_COUNTS 0
#define WS_OFF    4096
#define WS_CURSOR 12288
#define WS_PTS    16384

__device__ __forceinline__ int cell_coord(float v) {
    int c = (int)(v * INV_W);
    return c > (GDIM - 1) ? (GDIM - 1) : c;   // v in [0,1): c<=9 anyway; clamp for safety
}

__device__ __forceinline__ int prefix_lt(unsigned long long m) {
    return (int)__builtin_amdgcn_mbcnt_hi(
        (unsigned)(m >> 32),
        __builtin_amdgcn_mbcnt_lo((unsigned)m, 0u));
}

__global__ void k_count(const float* __restrict__ p2, int* __restrict__ counts) {
    int j = blockIdx.x * blockDim.x + threadIdx.x;
    if (j < N2) {
        float x = p2[3 * j], y = p2[3 * j + 1], z = p2[3 * j + 2];
        int c = (cell_coord(x) * GDIM + cell_coord(y)) * GDIM + cell_coord(z);
        atomicAdd(&counts[c], 1);
    }
}

__global__ __launch_bounds__(1024) void k_prefix(const int* __restrict__ counts,
                                                 int* __restrict__ off,
                                                 int* __restrict__ cursor) {
    __shared__ int s[1024];
    int t = threadIdx.x;
    int mine = (t < NCELLS) ? counts[t] : 0;
    s[t] = mine;
    __syncthreads();
    for (int d = 1; d < 1024; d <<= 1) {   // Hillis-Steele inclusive scan
        int v = (t >= d) ? s[t - d] : 0;
        __syncthreads();
        s[t] += v;
        __syncthreads();
    }
    if (t < NCELLS) {
        int excl = s[t] - mine;
        off[t] = excl;
        cursor[t] = excl;
    }
    if (t == NCELLS - 1) off[NCELLS] = s[t];   // total = N2
}

__global__ void k_scatter(const float* __restrict__ p2, int* __restrict__ cursor,
                          float4* __restrict__ pts) {
    int j = blockIdx.x * blockDim.x + threadIdx.x;
    if (j < N2) {
        float x = p2[3 * j], y = p2[3 * j + 1], z = p2[3 * j + 2];
        int c = (cell_coord(x) * GDIM + cell_coord(y)) * GDIM + cell_coord(z);
        int slot = atomicAdd(&cursor[c], 1);   // intra-cell order nondeterministic: fixed by sort
        pts[slot] = make_float4(x, y, z, (float)j);
    }
}

__global__ __launch_bounds__(256) void k_query(
    const float* __restrict__ p1, const float4* __restrict__ pts,
    const int* __restrict__ off,
    float* __restrict__ map_f, float* __restrict__ cnt_f, float* __restrict__ out_f)
{
    __shared__ float4 hits[4][HCAP];   // 8 KB, per-wave private
    const int w    = (int)(threadIdx.x >> 6);
    const int lane = (int)(threadIdx.x & 63);
    const int q    = (int)blockIdx.x * 4 + w;

    const float qx = p1[3 * q], qy = p1[3 * q + 1], qz = p1[3 * q + 2];
    // bit-exact numpy-style s1 (do not change)
    const float s1 = __fadd_rn(__fadd_rn(__fmul_rn(qx, qx), __fmul_rn(qy, qy)),
                               __fmul_rn(qz, qz));

    const int cx = cell_coord(qx), cy = cell_coord(qy), cz = cell_coord(qz);
    const int xlo = cx > 0 ? cx - 1 : 0, xhi = cx < GDIM - 1 ? cx + 1 : GDIM - 1;
    const int ylo = cy > 0 ? cy - 1 : 0, yhi = cy < GDIM - 1 ? cy + 1 : GDIM - 1;
    const int zlo = cz > 0 ? cz - 1 : 0, zhi = cz < GDIM - 1 ? cz + 1 : GDIM - 1;

    int cnt = 0;
    // 3x3 (x,y) columns; each column's 3 z-cells are contiguous in cell-id space,
    // hence contiguous in pts[] -> one [start,end) run per column.
    for (int ax = xlo; ax <= xhi; ++ax) {
        for (int ay = ylo; ay <= yhi; ++ay) {
            const int base  = (ax * GDIM + ay) * GDIM;
            const int start = off[base + zlo];
            const int end   = off[base + zhi + 1];
            for (int t = start + lane; ; t += 64) {
                const bool active = (t < end);
                if (!__ballot(active)) break;
                float4 e = make_float4(2.0f, 2.0f, 2.0f, 0.0f);  // dummy: far away
                if (active) e = pts[t];
                // bit-exact f32 gram classification (do not change)
                const float s2  = __fadd_rn(__fadd_rn(__fmul_rn(e.x, e.x), __fmul_rn(e.y, e.y)),
                                            __fmul_rn(e.z, e.z));
                const float dot = __fmaf_rn(qz, e.z, __fmaf_rn(qy, e.y, __fmul_rn(qx, e.x)));
                const float d2  = __fsub_rn(__fadd_rn(s1, s2), __fadd_rn(dot, dot));
                const bool within = active && (d2 <= R2_F32);
                const unsigned long long m = __ballot(within);
                if (m) {
                    const int pos = cnt + prefix_lt(m);
                    if (within && pos < HCAP) hits[w][pos] = e;
                    cnt += (int)__popcll(m);
                }
            }
        }
    }

    // Sort hits by original index j: key = (j<<7)|bufpos, 128-element bitonic,
    // 2 keys/lane (element e0=lane, e1=lane+64), ascending. Restores index order
    // lost to grid traversal + nondeterministic scatter.
    const int cap = cnt < HCAP ? cnt : HCAP;
    int k0 = 0x7FFFFFFF, k1 = 0x7FFFFFFF;
    if (lane < cap) {
        k0 = (((int)hits[w][lane].w) << 7) | lane;
    }
    if (lane + 64 < cap) {
        k1 = (((int)hits[w][lane + 64].w) << 7) | (lane + 64);
    }
    for (int k = 2; k <= 128; k <<= 1) {
        for (int s = k >> 1; s > 0; s >>= 1) {
            if (s == 64) {             // cross-reg, same lane (only at k=128): ascending
                const int lo = k0 < k1 ? k0 : k1;
                const int hi = k0 < k1 ? k1 : k0;
                k0 = lo; k1 = hi;
            } else {
                const int p0 = __shfl_xor(k0, s, 64);
                const int p1 = __shfl_xor(k1, s, 64);
                const bool lower = (lane & s) == 0;
                const bool asc0  = ((lane       ) & k) == 0;
                const bool asc1  = ((lane + 64  ) & k) == 0;
                k0 = (lower == asc0) ? (k0 < p0 ? k0 : p0) : (k0 > p0 ? k0 : p0);
                k1 = (lower == asc1) ? (k1 < p1 ? k1 : p1) : (k1 > p1 ? k1 : p1);
            }
        }
    }

    const int outc = cnt < KNN ? cnt : KNN;
    if (lane < KNN) {
        const int s = q * KNN + lane;
        float* o = out_f + s * 3;
        if (lane < outc) {
            const int bufpos = k0 & 127;
            const float4 e = hits[w][bufpos];
            map_f[s] = (float)(k0 >> 7);
            o[0] = e.x; o[1] = e.y; o[2] = e.z;
        } else {
            map_f[s] = 0.0f;
            o[0] = 0.0f; o[1] = 0.0f; o[2] = 0.0f;
        }
    }
    if (lane == 0) cnt_f[q] = (float)outc;
}

extern "C" void kernel_launch(void* const* d_in, const int* in_sizes, int n_in,
                              void* d_out, int out_size, void* d_ws, size_t ws_size,
                              hipStream_t stream) {
    const float* p1 = (const float*)d_in[0];
    const float* p2 = (const float*)d_in[1];
    float* out = (float*)d_out;

    float* map_f = out;                        // N1*KNN
    float* cnt_f = out + (size_t)N1 * KNN;     // N1
    float* out_f = cnt_f + N1;                 // N1*KNN*3

    char* ws = (char*)d_ws;
    int*    counts = (int*)(ws + WS_COUNTS);
    int*    off    = (int*)(ws + WS_OFF);
    int*    cursor = (int*)(ws + WS_CURSOR);
    float4* pts    = (float4*)(ws + WS_PTS);

    hipMemsetAsync(counts, 0, NCELLS * sizeof(int), stream);
    hipLaunchKernelGGL(k_count,   dim3(N2 / 256), dim3(256),  0, stream, p2, counts);
    hipLaunchKernelGGL(k_prefix,  dim3(1),        dim3(1024), 0, stream, counts, off, cursor);
    hipLaunchKernelGGL(k_scatter, dim3(N2 / 256), dim3(256),  0, stream, p2, cursor, pts);
    hipLaunchKernelGGL(k_query,   dim3(N1 / 4),   dim3(256),  0, stream,
                       p1, pts, off, map_f, cnt_f, out_f);
}

// Round 13
// 25.419 us; speedup vs baseline: 1.2119x; 1.2119x over previous
//
#include <hip/hip_runtime.h>

#define N1 8192
#define N2 8192
#define KNN 32
#define R2_F32 0.009999999776482582f   // f32(0.1*0.1), bit-exact vs np ref (rounds 2..12)

#define GDIM 10
#define NCELLS (GDIM * GDIM * GDIM)
// cell width 7/64 = 0.109375; INV_W = 64/7. Non-adjacent cells => coord gap >= 0.109
// => true d2 >= 0.0119 >> 0.01 + gram-noise(~6e-7): grid can never drop a reference hit.
#define INV_W 9.142857142857142f
#define HCAP 128   // per-query hit buffer (E[hits]~34; P(>128) ~ 0)

// ---- ws layout (bytes) ----
// 0    : off  [1001] i32
// 4096 : pts4 [8192] float4 (x,y,z,(float)j), grouped by cell
#define WS_OFF 0
#define WS_PTS 4096

__device__ __forceinline__ int cell_coord(float v) {
    int c = (int)(v * INV_W);
    return c > (GDIM - 1) ? (GDIM - 1) : c;
}

__device__ __forceinline__ int prefix_lt(unsigned long long m) {
    return (int)__builtin_amdgcn_mbcnt_hi(
        (unsigned)(m >> 32),
        __builtin_amdgcn_mbcnt_lo((unsigned)m, 0u));
}

// Single-block grid build: histogram -> scan -> scatter, all via LDS.
// Points ride in registers between phases (no re-read).
#define BT 1024
#define PPT (N2 / BT)   // 8 points per thread
__global__ __launch_bounds__(BT) void k_build(const float* __restrict__ p2,
                                              int* __restrict__ off_g,
                                              float4* __restrict__ pts) {
    __shared__ int cnt_s[NCELLS];   // counts, then reused as scatter cursor
    __shared__ int scan_s[BT];
    const int t = (int)threadIdx.x;

    for (int i = t; i < NCELLS; i += BT) cnt_s[i] = 0;
    __syncthreads();

    float4 pt[PPT];
    int    cid[PPT];
#pragma unroll
    for (int r = 0; r < PPT; ++r) {
        const int j = r * BT + t;   // coalesced
        const float x = p2[3 * j], y = p2[3 * j + 1], z = p2[3 * j + 2];
        const int c = (cell_coord(x) * GDIM + cell_coord(y)) * GDIM + cell_coord(z);
        pt[r]  = make_float4(x, y, z, (float)j);
        cid[r] = c;
        atomicAdd(&cnt_s[c], 1);
    }
    __syncthreads();

    const int mine = (t < NCELLS) ? cnt_s[t] : 0;
    scan_s[t] = mine;
    __syncthreads();
    for (int d = 1; d < BT; d <<= 1) {   // Hillis-Steele inclusive scan
        const int v = (t >= d) ? scan_s[t - d] : 0;
        __syncthreads();
        scan_s[t] += v;
        __syncthreads();
    }
    if (t < NCELLS) {
        const int excl = scan_s[t] - mine;
        off_g[t] = excl;
        cnt_s[t] = excl;                 // cursor
    }
    if (t == NCELLS - 1) off_g[NCELLS] = scan_s[t];  // = N2
    __syncthreads();

#pragma unroll
    for (int r = 0; r < PPT; ++r) {
        const int slot = atomicAdd(&cnt_s[cid[r]], 1);  // intra-cell order fixed later by sort
        pts[slot] = pt[r];
    }
}

__global__ __launch_bounds__(256) void k_query(
    const float* __restrict__ p1, const float4* __restrict__ pts,
    const int* __restrict__ off,
    float* __restrict__ map_f, float* __restrict__ cnt_f, float* __restrict__ out_f)
{
    __shared__ float4 hits[4][HCAP];   // 8 KB, per-wave private
    const int w    = (int)(threadIdx.x >> 6);
    const int lane = (int)(threadIdx.x & 63);
    const int q    = (int)blockIdx.x * 4 + w;

    const float qx = p1[3 * q], qy = p1[3 * q + 1], qz = p1[3 * q + 2];
    // bit-exact numpy-style s1 (do not change)
    const float s1 = __fadd_rn(__fadd_rn(__fmul_rn(qx, qx), __fmul_rn(qy, qy)),
                               __fmul_rn(qz, qz));

    const int cx = cell_coord(qx), cy = cell_coord(qy), cz = cell_coord(qz);
    const int xlo = cx > 0 ? cx - 1 : 0, xhi = cx < GDIM - 1 ? cx + 1 : GDIM - 1;
    const int ylo = cy > 0 ? cy - 1 : 0, yhi = cy < GDIM - 1 ? cy + 1 : GDIM - 1;
    const int zlo = cz > 0 ? cz - 1 : 0, zhi = cz < GDIM - 1 ? cz + 1 : GDIM - 1;

    int cnt = 0;
    // 3x3 (x,y) columns; each column's z-cells are contiguous in pts[].
    for (int ax = xlo; ax <= xhi; ++ax) {
        for (int ay = ylo; ay <= yhi; ++ay) {
            const int base  = (ax * GDIM + ay) * GDIM;
            const int start = off[base + zlo];
            const int end   = off[base + zhi + 1];
            for (int t = start + lane; ; t += 64) {
                const bool active = (t < end);
                if (!__ballot(active)) break;
                float4 e = make_float4(2.0f, 2.0f, 2.0f, 0.0f);  // dummy: far away
                if (active) e = pts[t];
                // bit-exact f32 gram classification (do not change)
                const float s2  = __fadd_rn(__fadd_rn(__fmul_rn(e.x, e.x), __fmul_rn(e.y, e.y)),
                                            __fmul_rn(e.z, e.z));
                const float dot = __fmaf_rn(qz, e.z, __fmaf_rn(qy, e.y, __fmul_rn(qx, e.x)));
                const float d2  = __fsub_rn(__fadd_rn(s1, s2), __fadd_rn(dot, dot));
                const bool within = active && (d2 <= R2_F32);
                const unsigned long long m = __ballot(within);
                if (m) {
                    const int pos = cnt + prefix_lt(m);
                    if (within && pos < HCAP) hits[w][pos] = e;
                    cnt += (int)__popcll(m);
                }
            }
        }
    }

    // Restore index order: key = (j<<7)|bufpos, 128-element bitonic sort,
    // 2 keys/lane (e0=lane, e1=lane+64), ascending.
    const int cap = cnt < HCAP ? cnt : HCAP;
    int k0 = 0x7FFFFFFF, k1 = 0x7FFFFFFF;
    if (lane < cap)      k0 = (((int)hits[w][lane].w) << 7) | lane;
    if (lane + 64 < cap) k1 = (((int)hits[w][lane + 64].w) << 7) | (lane + 64);
    for (int k = 2; k <= 128; k <<= 1) {
        for (int s = k >> 1; s > 0; s >>= 1) {
            if (s == 64) {             // cross-reg, same lane (only at k=128): ascending
                const int lo = k0 < k1 ? k0 : k1;
                const int hi = k0 < k1 ? k1 : k0;
                k0 = lo; k1 = hi;
            } else {
                const int p0 = __shfl_xor(k0, s, 64);
                const int p1 = __shfl_xor(k1, s, 64);
                const bool lower = (lane & s) == 0;
                const bool asc0  = ((lane     ) & k) == 0;
                const bool asc1  = ((lane + 64) & k) == 0;
                k0 = (lower == asc0) ? (k0 < p0 ? k0 : p0) : (k0 > p0 ? k0 : p0);
                k1 = (lower == asc1) ? (k1 < p1 ? k1 : p1) : (k1 > p1 ? k1 : p1);
            }
        }
    }

    const int outc = cnt < KNN ? cnt : KNN;
    if (lane < KNN) {
        const int s = q * KNN + lane;
        float* o = out_f + s * 3;
        if (lane < outc) {
            const int bufpos = k0 & 127;
            const float4 e = hits[w][bufpos];
            map_f[s] = (float)(k0 >> 7);
            o[0] = e.x; o[1] = e.y; o[2] = e.z;
        } else {
            map_f[s] = 0.0f;
            o[0] = 0.0f; o[1] = 0.0f; o[2] = 0.0f;
        }
    }
    if (lane == 0) cnt_f[q] = (float)outc;
}

extern "C" void kernel_launch(void* const* d_in, const int* in_sizes, int n_in,
                              void* d_out, int out_size, void* d_ws, size_t ws_size,
                              hipStream_t stream) {
    const float* p1 = (const float*)d_in[0];
    const float* p2 = (const float*)d_in[1];
    float* out = (float*)d_out;

    float* map_f = out;                        // N1*KNN
    float* cnt_f = out + (size_t)N1 * KNN;     // N1
    float* out_f = cnt_f + N1;                 // N1*KNN*3

    char* ws = (char*)d_ws;
    int*    off = (int*)(ws + WS_OFF);
    float4* pts = (float4*)(ws + WS_PTS);

    hipLaunchKernelGGL(k_build, dim3(1),      dim3(BT),  0, stream, p2, off, pts);
    hipLaunchKernelGGL(k_query, dim3(N1 / 4), dim3(256), 0, stream,
                       p1, pts, off, map_f, cnt_f, out_f);
}

// Round 14
// 23.761 us; speedup vs baseline: 1.2965x; 1.0697x over previous
//
#include <hip/hip_runtime.h>

#define N1 8192
#define N2 8192
#define KNN 32
#define R2_F32 0.009999999776482582f   // f32(0.1*0.1), bit-exact vs np ref (rounds 2..13)

#define GDIM 10
#define NCELLS (GDIM * GDIM * GDIM)
#define CELL_W 0.109375f               // 7/64: exact in f32, all ax*CELL_W products exact
#define INV_W  9.142857142857142f
#define CAP 40                         // bucket capacity; lambda=10.7 -> P(overflow) ~ 5e-8
#define HCAP 128                       // per-query hit buffer (E[hits]~34)
#define PRUNE2 0.0105f                 // cell min-dist^2 prune threshold (margin >> gram noise)

// ---- ws layout ----
// 0    : cnt [1000] i32 (memsetAsync'd to 0 each launch)
// 4096 : pts [1000*CAP] float4 (x,y,z,(float)j)   = 640 KB
#define WS_CNT 0
#define WS_PTS 4096

__device__ __forceinline__ int cell_coord(float v) {
    int c = (int)(v * INV_W);
    return c > (GDIM - 1) ? (GDIM - 1) : c;
}

__device__ __forceinline__ int prefix_lt(unsigned long long m) {
    return (int)__builtin_amdgcn_mbcnt_hi(
        (unsigned)(m >> 32),
        __builtin_amdgcn_mbcnt_lo((unsigned)m, 0u));
}

// Fully-parallel one-pass build: direct bucket scatter (no count pass, no scan).
__global__ __launch_bounds__(256) void k_scatter(const float* __restrict__ p2,
                                                 int* __restrict__ cnt,
                                                 float4* __restrict__ pts) {
    const int j = (int)(blockIdx.x * blockDim.x + threadIdx.x);
    if (j < N2) {
        const float x = p2[3 * j], y = p2[3 * j + 1], z = p2[3 * j + 2];
        const int c = (cell_coord(x) * GDIM + cell_coord(y)) * GDIM + cell_coord(z);
        const int slot = atomicAdd(&cnt[c], 1);   // intra-cell order nondet: fixed by sort
        if (slot < CAP) pts[c * CAP + slot] = make_float4(x, y, z, (float)j);
    }
}

__global__ __launch_bounds__(256) void k_query(
    const float* __restrict__ p1, const float4* __restrict__ pts,
    const int* __restrict__ cnt,
    float* __restrict__ map_f, float* __restrict__ cnt_f, float* __restrict__ out_f)
{
    __shared__ float4 hits[4][HCAP];    // 8 KB, per-wave private
    __shared__ int cum_l[4][32];        // inclusive prefix of kept-run lengths
    __shared__ int adj_l[4][32];        // pts-index adjustment per run
    const int w    = (int)(threadIdx.x >> 6);
    const int lane = (int)(threadIdx.x & 63);
    const int q    = (int)blockIdx.x * 4 + w;

    const float qx = p1[3 * q], qy = p1[3 * q + 1], qz = p1[3 * q + 2];
    // bit-exact numpy-style s1 (do not change)
    const float s1 = __fadd_rn(__fadd_rn(__fmul_rn(qx, qx), __fmul_rn(qy, qy)),
                               __fmul_rn(qz, qz));

    const int cx = cell_coord(qx), cy = cell_coord(qy), cz = cell_coord(qz);

    // Lanes 0..26 own one neighbor cell each: length + min-dist^2 prune.
    int len = 0, id = 0;
    if (lane < 27) {
        const int ax = cx + lane / 9 - 1;
        const int ay = cy + (lane / 3) % 3 - 1;
        const int az = cz + lane % 3 - 1;
        const bool valid = (unsigned)ax < GDIM && (unsigned)ay < GDIM && (unsigned)az < GDIM;
        if (valid) {
            id = (ax * GDIM + ay) * GDIM + az;
            // per-axis gap from q to the cell's AABB (ax*CELL_W etc. are exact f32)
            const float gx = fmaxf(0.0f, fmaxf((float)ax * CELL_W - qx, qx - (float)(ax + 1) * CELL_W));
            const float gy = fmaxf(0.0f, fmaxf((float)ay * CELL_W - qy, qy - (float)(ay + 1) * CELL_W));
            const float gz = fmaxf(0.0f, fmaxf((float)az * CELL_W - qz, qz - (float)(az + 1) * CELL_W));
            const float mind2 = gx * gx + gy * gy + gz * gz;
            if (mind2 <= PRUNE2) {
                int c = cnt[id];
                len = c < CAP ? c : CAP;
            }
        }
    }

    // Inclusive scan of len over lanes (only 0..31 meaningful; lanes>=27 have len=0
    // so cum[27..31] == T automatically).
    int cum = len;
#pragma unroll
    for (int d = 1; d < 32; d <<= 1) {
        const int v = __shfl_up(cum, d, 64);
        if (lane >= d) cum += v;
    }
    const int T = __shfl(cum, 26, 64);
    if (lane < 32) {
        cum_l[w][lane] = cum;
        adj_l[w][lane] = id * CAP - (cum - len);   // pts_idx = g + adj[run]
    }

    // Dense gather over the virtual concatenation of kept runs: all lanes active.
    int hcnt = 0;
    for (int g0 = 0; g0 < T; g0 += 64) {
        const int g = g0 + lane;
        const bool active = g < T;
        int lo = 0;   // smallest r with cum[r] > g (5-step binary search over 32)
#pragma unroll
        for (int st = 16; st > 0; st >>= 1)
            if (cum_l[w][lo + st - 1] <= g) lo += st;
        float4 e = make_float4(2.0f, 2.0f, 2.0f, 0.0f);   // dummy: far away
        if (active) e = pts[g + adj_l[w][lo]];
        // bit-exact f32 gram classification (do not change)
        const float s2  = __fadd_rn(__fadd_rn(__fmul_rn(e.x, e.x), __fmul_rn(e.y, e.y)),
                                    __fmul_rn(e.z, e.z));
        const float dot = __fmaf_rn(qz, e.z, __fmaf_rn(qy, e.y, __fmul_rn(qx, e.x)));
        const float d2  = __fsub_rn(__fadd_rn(s1, s2), __fadd_rn(dot, dot));
        const bool within = active && (d2 <= R2_F32);
        const unsigned long long m = __ballot(within);
        if (m) {
            const int pos = hcnt + prefix_lt(m);
            if (within && pos < HCAP) hits[w][pos] = e;
            hcnt += (int)__popcll(m);
        }
    }

    // Restore index order: key = (j<<7)|bufpos, 128-element bitonic sort,
    // 2 keys/lane (e0=lane, e1=lane+64), ascending. (verbatim from round 13)
    const int cap = hcnt < HCAP ? hcnt : HCAP;
    int k0 = 0x7FFFFFFF, k1 = 0x7FFFFFFF;
    if (lane < cap)      k0 = (((int)hits[w][lane].w) << 7) | lane;
    if (lane + 64 < cap) k1 = (((int)hits[w][lane + 64].w) << 7) | (lane + 64);
    for (int k = 2; k <= 128; k <<= 1) {
        for (int s = k >> 1; s > 0; s >>= 1) {
            if (s == 64) {
                const int lo2 = k0 < k1 ? k0 : k1;
                const int hi2 = k0 < k1 ? k1 : k0;
                k0 = lo2; k1 = hi2;
            } else {
                const int p0 = __shfl_xor(k0, s, 64);
                const int p1 = __shfl_xor(k1, s, 64);
                const bool lower = (lane & s) == 0;
                const bool asc0  = ((lane     ) & k) == 0;
                const bool asc1  = ((lane + 64) & k) == 0;
                k0 = (lower == asc0) ? (k0 < p0 ? k0 : p0) : (k0 > p0 ? k0 : p0);
                k1 = (lower == asc1) ? (k1 < p1 ? k1 : p1) : (k1 > p1 ? k1 : p1);
            }
        }
    }

    const int outc = hcnt < KNN ? hcnt : KNN;
    if (lane < KNN) {
        const int s = q * KNN + lane;
        float* o = out_f + s * 3;
        if (lane < outc) {
            const float4 e = hits[w][k0 & 127];
            map_f[s] = (float)(k0 >> 7);
            o[0] = e.x; o[1] = e.y; o[2] = e.z;
        } else {
            map_f[s] = 0.0f;
            o[0] = 0.0f; o[1] = 0.0f; o[2] = 0.0f;
        }
    }
    if (lane == 0) cnt_f[q] = (float)outc;
}

extern "C" void kernel_launch(void* const* d_in, const int* in_sizes, int n_in,
                              void* d_out, int out_size, void* d_ws, size_t ws_size,
                              hipStream_t stream) {
    const float* p1 = (const float*)d_in[0];
    const float* p2 = (const float*)d_in[1];
    float* out = (float*)d_out;

    float* map_f = out;                        // N1*KNN
    float* cnt_f = out + (size_t)N1 * KNN;     // N1
    float* out_f = cnt_f + N1;                 // N1*KNN*3

    char* ws = (char*)d_ws;
    int*    cnt = (int*)(ws + WS_CNT);
    float4* pts = (float4*)(ws + WS_PTS);

    hipMemsetAsync(cnt, 0, NCELLS * sizeof(int), stream);
    hipLaunchKernelGGL(k_scatter, dim3(N2 / 256), dim3(256), 0, stream, p2, cnt, pts);
    hipLaunchKernelGGL(k_query,   dim3(N1 / 4),   dim3(256), 0, stream,
                       p1, pts, cnt, map_f, cnt_f, out_f);
}